// Round 8
// baseline (459.577 us; speedup 1.0000x reference)
//
#include <hip/hip_runtime.h>
#include <hip/hip_bf16.h>

// MoE FFN, grouped sparse dispatch (top-2 of 8).
// BM=256 GEMM tiles (min weight re-fetch) with narrow N-panels for fine-grained
// round balance; dbuf + counted vmcnt + raw barriers (R4/R6 schedule); T2 LDS
// XOR-swizzle both-sides; bf16 partials; fused weight conversion.

#define T_TOKENS 8192
#define HID 1024
#define NEXP 8
#define ED 2048
#define ED2 4096
#define MAXT256 72      // max 256-row tiles

typedef __hip_bfloat16 bf16;
typedef __attribute__((ext_vector_type(8))) short bf16x8;
typedef __attribute__((ext_vector_type(4))) float f32x4;

#define WAITVM(N) asm volatile("s_waitcnt vmcnt(" #N ")" ::: "memory")
#define BAR() asm volatile("s_barrier" ::: "memory")

__device__ __forceinline__ void gload_lds16(const void* g, void* lds) {
  __builtin_amdgcn_global_load_lds(
      (const __attribute__((address_space(1))) void*)g,
      (__attribute__((address_space(3))) void*)lds, 16, 0, 0);
}

__device__ __forceinline__ bf16x8 lds_read_swz(const bf16* base, int row, int kb) {
  int off = row * 128 + (kb ^ ((row & 7) << 4));
  return *reinterpret_cast<const bf16x8*>(reinterpret_cast<const char*>(base) + off);
}

// ---------------- f32 -> bf16 conversion (both weight tensors, one launch) ----------------
__global__ void cvt2_kernel(const float* __restrict__ up, const float* __restrict__ down,
                            bf16* __restrict__ upb, bf16* __restrict__ downb) {
  const int n_up4 = (NEXP * ED2 * HID) / 4;
  const int n_total = n_up4 + (NEXP * HID * ED) / 4;
  int idx = blockIdx.x * blockDim.x + threadIdx.x;
  int stride = gridDim.x * blockDim.x;
  for (int i = idx; i < n_total; i += stride) {
    const float4 v = (i < n_up4) ? reinterpret_cast<const float4*>(up)[i]
                                 : reinterpret_cast<const float4*>(down)[i - n_up4];
    bf16 h0 = __float2bfloat16(v.x), h1 = __float2bfloat16(v.y);
    bf16 h2 = __float2bfloat16(v.z), h3 = __float2bfloat16(v.w);
    ushort4 o;
    o.x = *reinterpret_cast<unsigned short*>(&h0);
    o.y = *reinterpret_cast<unsigned short*>(&h1);
    o.z = *reinterpret_cast<unsigned short*>(&h2);
    o.w = *reinterpret_cast<unsigned short*>(&h3);
    if (i < n_up4) reinterpret_cast<ushort4*>(upb)[i] = o;
    else reinterpret_cast<ushort4*>(downb)[i - n_up4] = o;
  }
}

// ---------------- router (+ x -> bf16) ----------------
__global__ __launch_bounds__(64) void router_kernel(const float* __restrict__ x,
                                                    const float* __restrict__ rw,
                                                    bf16* __restrict__ xb,
                                                    int2* __restrict__ top2i,
                                                    float2* __restrict__ top2w) {
  const int t = blockIdx.x;
  const int lane = threadIdx.x;
  const float* xr = x + (size_t)t * HID;
  float xv[16];
#pragma unroll
  for (int i = 0; i < 16; i++) xv[i] = xr[lane + 64 * i];
#pragma unroll
  for (int i = 0; i < 16; i++) xb[(size_t)t * HID + lane + 64 * i] = __float2bfloat16(xv[i]);
  float logit[NEXP];
#pragma unroll
  for (int e = 0; e < NEXP; e++) {
    const float* r = rw + e * HID;
    float p = 0.f;
#pragma unroll
    for (int i = 0; i < 16; i++) p += xv[i] * r[lane + 64 * i];
#pragma unroll
    for (int off = 32; off > 0; off >>= 1) p += __shfl_down(p, off);
    logit[e] = __shfl(p, 0);
  }
  if (lane == 0) {
    int i0 = 0;
    for (int e = 1; e < NEXP; e++) if (logit[e] > logit[i0]) i0 = e;
    int i1 = (i0 == 0) ? 1 : 0;
    for (int e = 0; e < NEXP; e++) if (e != i0 && logit[e] > logit[i1]) i1 = e;
    float m = fmaxf(logit[i0], logit[i1]);
    float p0 = expf(logit[i0] - m), p1 = expf(logit[i1] - m);
    float s = p0 + p1;
    top2i[t] = make_int2(i0, i1);
    top2w[t] = make_float2(p0 / s, p1 / s);
  }
}

// ---------------- list build (pad to 256) ----------------
__global__ __launch_bounds__(512) void build_lists(const int2* __restrict__ top2i,
                                                   int* __restrict__ list,
                                                   int2* __restrict__ posArr,
                                                   int* __restrict__ tile_e,
                                                   int* __restrict__ meta) {
  __shared__ int s_cnt[NEXP];
  __shared__ int s_base[NEXP + 1];
  const int e = threadIdx.x >> 6;
  const int lane = threadIdx.x & 63;

  int cnt = 0;
  for (int c = 0; c < T_TOKENS / 64; c++) {
    const int t = c * 64 + lane;
    int2 ti = top2i[t];
    cnt += __popcll(__ballot((ti.x == e) || (ti.y == e)));
  }
  if (lane == 0) s_cnt[e] = cnt;
  __syncthreads();
  if (threadIdx.x == 0) {
    int acc = 0;
    for (int i = 0; i < NEXP; i++) {
      s_base[i] = acc;
      acc += (s_cnt[i] + 255) & ~255;
    }
    s_base[NEXP] = acc;
    meta[0] = acc / 256;
  }
  __syncthreads();
  const int ebase = s_base[e];
  const int padded = (s_cnt[e] + 255) & ~255;

  int base = 0;
  for (int c = 0; c < T_TOKENS / 64; c++) {
    const int t = c * 64 + lane;
    int2 ti = top2i[t];
    bool a0 = (ti.x == e);
    bool assigned = a0 || (ti.y == e);
    unsigned long long bal = __ballot(assigned);
    int prefix = __popcll(bal & ((1ull << lane) - 1ull));
    if (assigned) {
      int g = ebase + base + prefix;
      list[g] = t;
      if (a0) posArr[t].x = g; else posArr[t].y = g;
    }
    base += __popcll(bal);
  }
  for (int p = base + lane; p < padded; p += 64) list[ebase + p] = 0;
  for (int i = lane; i < padded / 256; i += 64) tile_e[ebase / 256 + i] = e;
}

// ---------------- GEMM1: y1 = silu(x@Wg^T)*(x@Wu^T), 256 rows x 64 dual cols ----------------
// 8 waves 2M x 4N; per wave 128 rows x 16 cols of gate AND up.
__global__ __launch_bounds__(512) void gemm1_silu(const bf16* __restrict__ A,
                                                  const bf16* __restrict__ Ball,
                                                  bf16* __restrict__ Y,
                                                  const int* __restrict__ list,
                                                  const int* __restrict__ tile_e,
                                                  const int* __restrict__ meta) {
  __shared__ bf16 sA[2][256 * 64];
  __shared__ bf16 sBg[2][64 * 64];
  __shared__ bf16 sBu[2][64 * 64];
  const int nwg = MAXT256 * 32;               // 2304, %8==0
  const int id2 = ((int)blockIdx.x % 8) * (nwg / 8) + (int)blockIdx.x / 8;  // T1
  const int dn = id2 & 31;
  const int tile = id2 >> 5;
  if (tile >= meta[0]) return;
  const bf16* B = Ball + (size_t)tile_e[tile] * (ED2 * HID);
  const int rowbase = tile * 256;
  const int w = threadIdx.x >> 6, lane = threadIdx.x & 63;
  const int wm = w >> 2, wn = w & 3;
  const int srcswz = 16 * ((lane & 7) ^ ((lane >> 3) & 7));
  const int dn0 = dn * 64;

  int tok[4];
#pragma unroll
  for (int i = 0; i < 4; i++) tok[i] = list[rowbase + w * 32 + i * 8 + (lane >> 3)];

  f32x4 accg[8] = {};
  f32x4 accu[8] = {};

  auto stage = [&](int kt, int buf) {
    const int kb0 = kt * 128;
#pragma unroll
    for (int i = 0; i < 4; i++)
      gload_lds16((const char*)A + (size_t)tok[i] * (HID * 2) + kb0 + srcswz,
                  (char*)&sA[buf][0] + (w * 32 + i * 8) * 128);
    const int grow = dn0 + w * 8 + (lane >> 3);
    gload_lds16((const char*)B + (size_t)grow * (HID * 2) + kb0 + srcswz,
                (char*)&sBg[buf][0] + w * 1024);
    gload_lds16((const char*)B + (size_t)(ED + grow) * (HID * 2) + kb0 + srcswz,
                (char*)&sBu[buf][0] + w * 1024);
  };

  const int arow0 = wm * 128 + (lane & 15);
  const int brow0 = wn * 16 + (lane & 15);
  const int kb0 = (lane >> 4) * 16;

  const int NT = HID / 64;  // 16
  stage(0, 0);
  for (int t = 0; t < NT; ++t) {
    const int cur = t & 1;
    if (t + 1 < NT) { stage(t + 1, cur ^ 1); WAITVM(6); }
    else { WAITVM(0); }
    BAR();
    const bf16* pA = &sA[cur][0];
    const bf16* pBg = &sBg[cur][0];
    const bf16* pBu = &sBu[cur][0];
    bf16x8 a[4][2], bg[2], bu[2];
    // q0: A m0..3 + Bg reads, gate MFMA m0..3
#pragma unroll
    for (int m = 0; m < 4; m++)
#pragma unroll
      for (int ks = 0; ks < 2; ks++) a[m][ks] = lds_read_swz(pA, arow0 + m * 16, kb0 + ks * 64);
#pragma unroll
    for (int ks = 0; ks < 2; ks++) bg[ks] = lds_read_swz(pBg, brow0, kb0 + ks * 64);
    __builtin_amdgcn_s_setprio(1);
#pragma unroll
    for (int m = 0; m < 4; m++)
#pragma unroll
      for (int ks = 0; ks < 2; ks++)
        accg[m] = __builtin_amdgcn_mfma_f32_16x16x32_bf16(a[m][ks], bg[ks], accg[m], 0, 0, 0);
    __builtin_amdgcn_s_setprio(0);
    // q1: Bu reads, up MFMA m0..3
#pragma unroll
    for (int ks = 0; ks < 2; ks++) bu[ks] = lds_read_swz(pBu, brow0, kb0 + ks * 64);
    __builtin_amdgcn_s_setprio(1);
#pragma unroll
    for (int m = 0; m < 4; m++)
#pragma unroll
      for (int ks = 0; ks < 2; ks++)
        accu[m] = __builtin_amdgcn_mfma_f32_16x16x32_bf16(a[m][ks], bu[ks], accu[m], 0, 0, 0);
    __builtin_amdgcn_s_setprio(0);
    // q2: A m4..7 reads, gate MFMA m4..7
#pragma unroll
    for (int m = 0; m < 4; m++)
#pragma unroll
      for (int ks = 0; ks < 2; ks++) a[m][ks] = lds_read_swz(pA, arow0 + 64 + m * 16, kb0 + ks * 64);
    __builtin_amdgcn_s_setprio(1);
#pragma unroll
    for (int m = 0; m < 4; m++)
#pragma unroll
      for (int ks = 0; ks < 2; ks++)
        accg[m + 4] = __builtin_amdgcn_mfma_f32_16x16x32_bf16(a[m][ks], bg[ks], accg[m + 4], 0, 0, 0);
    __builtin_amdgcn_s_setprio(0);
    // q3: up MFMA m4..7
    __builtin_amdgcn_s_setprio(1);
#pragma unroll
    for (int m = 0; m < 4; m++)
#pragma unroll
      for (int ks = 0; ks < 2; ks++)
        accu[m + 4] = __builtin_amdgcn_mfma_f32_16x16x32_bf16(a[m][ks], bu[ks], accu[m + 4], 0, 0, 0);
    __builtin_amdgcn_s_setprio(0);
    BAR();
  }
  // epilogue: silu(g)*u -> bf16
#pragma unroll
  for (int m = 0; m < 8; m++) {
    const int row = rowbase + wm * 128 + (m & 3) * 16 + (m >> 2) * 64 + (lane >> 4) * 4;
    const int col = dn0 + wn * 16 + (lane & 15);
#pragma unroll
    for (int r = 0; r < 4; r++) {
      float g = accg[m][r];
      float u = accu[m][r];
      float s = g * __builtin_amdgcn_rcpf(1.f + exp2f(g * -1.44269504f));
      Y[(size_t)(row + r) * ED + col] = __float2bfloat16(s * u);
    }
  }
}

// ---------------- GEMM2: part = y1 @ down_e^T (bf16, unweighted), 256x128 ----------------
// 8 waves 2M x 4N; per wave 128 rows x 32 cols.
__global__ __launch_bounds__(512) void gemm2_part(const bf16* __restrict__ A,
                                                  const bf16* __restrict__ Ball,
                                                  bf16* __restrict__ part,
                                                  const int* __restrict__ tile_e,
                                                  const int* __restrict__ meta) {
  __shared__ bf16 sA[2][256 * 64];
  __shared__ bf16 sB[2][128 * 64];
  const int nwg = MAXT256 * 8;                // 576, %8==0
  const int id2 = ((int)blockIdx.x % 8) * (nwg / 8) + (int)blockIdx.x / 8;  // T1
  const int bn = id2 & 7;
  const int tile = id2 >> 3;
  if (tile >= meta[0]) return;
  const bf16* B = Ball + (size_t)tile_e[tile] * (HID * ED);
  const int rowbase = tile * 256;
  const int w = threadIdx.x >> 6, lane = threadIdx.x & 63;
  const int wm = w >> 2, wn = w & 3;
  const int srcswz = 16 * ((lane & 7) ^ ((lane >> 3) & 7));
  const int bn0 = bn * 128;

  f32x4 acc[8][2] = {};

  auto stage = [&](int kt, int buf) {
    const int kb0 = kt * 128;
#pragma unroll
    for (int i = 0; i < 4; i++) {
      const int c = w * 4 + i;
      gload_lds16((const char*)A + (size_t)(rowbase + c * 8 + (lane >> 3)) * (ED * 2) + kb0 + srcswz,
                  (char*)&sA[buf][0] + c * 1024);
    }
#pragma unroll
    for (int i = 0; i < 2; i++) {
      const int c = w * 2 + i;
      gload_lds16((const char*)B + (size_t)(bn0 + c * 8 + (lane >> 3)) * (ED * 2) + kb0 + srcswz,
                  (char*)&sB[buf][0] + c * 1024);
    }
  };

  const int arow0 = wm * 128 + (lane & 15);
  const int brow0 = wn * 32 + (lane & 15);
  const int kb0 = (lane >> 4) * 16;

  const int NT = ED / 64;  // 32
  stage(0, 0);
  for (int t = 0; t < NT; ++t) {
    const int cur = t & 1;
    if (t + 1 < NT) { stage(t + 1, cur ^ 1); WAITVM(6); }
    else { WAITVM(0); }
    BAR();
    const bf16* pA = &sA[cur][0];
    const bf16* pB = &sB[cur][0];
    bf16x8 a[4][2], b[2][2];
#pragma unroll
    for (int n = 0; n < 2; n++)
#pragma unroll
      for (int ks = 0; ks < 2; ks++) b[n][ks] = lds_read_swz(pB, brow0 + n * 16, kb0 + ks * 64);
    // mh0: m0..3
#pragma unroll
    for (int m = 0; m < 4; m++)
#pragma unroll
      for (int ks = 0; ks < 2; ks++) a[m][ks] = lds_read_swz(pA, arow0 + m * 16, kb0 + ks * 64);
    __builtin_amdgcn_s_setprio(1);
#pragma unroll
    for (int m = 0; m < 4; m++)
#pragma unroll
      for (int n = 0; n < 2; n++)
#pragma unroll
        for (int ks = 0; ks < 2; ks++)
          acc[m][n] = __builtin_amdgcn_mfma_f32_16x16x32_bf16(a[m][ks], b[n][ks], acc[m][n], 0, 0, 0);
    __builtin_amdgcn_s_setprio(0);
    // mh1: m4..7
#pragma unroll
    for (int m = 0; m < 4; m++)
#pragma unroll
      for (int ks = 0; ks < 2; ks++) a[m][ks] = lds_read_swz(pA, arow0 + 64 + m * 16, kb0 + ks * 64);
    __builtin_amdgcn_s_setprio(1);
#pragma unroll
    for (int m = 0; m < 4; m++)
#pragma unroll
      for (int n = 0; n < 2; n++)
#pragma unroll
        for (int ks = 0; ks < 2; ks++)
          acc[m + 4][n] = __builtin_amdgcn_mfma_f32_16x16x32_bf16(a[m][ks], b[n][ks], acc[m + 4][n], 0, 0, 0);
    __builtin_amdgcn_s_setprio(0);
    BAR();
  }
#pragma unroll
  for (int m = 0; m < 8; m++)
#pragma unroll
    for (int n = 0; n < 2; n++) {
      const int row = rowbase + wm * 128 + (m & 3) * 16 + (m >> 2) * 64 + (lane >> 4) * 4;
      const int col = bn0 + wn * 32 + n * 16 + (lane & 15);
#pragma unroll
      for (int r = 0; r < 4; r++)
        part[(size_t)(row + r) * HID + col] = __float2bfloat16(acc[m][n][r]);
    }
}

// ---------------- combine: out[t] = w0*part[pos0] + w1*part[pos1] (bf16 partials) ----------------
__global__ void combine_kernel(const bf16* __restrict__ part,
                               const int2* __restrict__ posArr,
                               const float2* __restrict__ top2w,
                               float* __restrict__ out) {
  const int total = T_TOKENS * (HID / 4);
  int idx = blockIdx.x * blockDim.x + threadIdx.x;
  int stride = gridDim.x * blockDim.x;
  for (int i = idx; i < total; i += stride) {
    const int t = i >> 8;
    const int c = i & 255;
    int2 p = posArr[t];
    float2 w = top2w[t];
    ushort4 av = reinterpret_cast<const ushort4*>(part)[(size_t)p.x * 256 + c];
    ushort4 bv = reinterpret_cast<const ushort4*>(part)[(size_t)p.y * 256 + c];
    float4 o;
    o.x = w.x * __bfloat162float(*reinterpret_cast<bf16*>(&av.x)) + w.y * __bfloat162float(*reinterpret_cast<bf16*>(&bv.x));
    o.y = w.x * __bfloat162float(*reinterpret_cast<bf16*>(&av.y)) + w.y * __bfloat162float(*reinterpret_cast<bf16*>(&bv.y));
    o.z = w.x * __bfloat162float(*reinterpret_cast<bf16*>(&av.z)) + w.y * __bfloat162float(*reinterpret_cast<bf16*>(&bv.z));
    o.w = w.x * __bfloat162float(*reinterpret_cast<bf16*>(&av.w)) + w.y * __bfloat162float(*reinterpret_cast<bf16*>(&bv.w));
    reinterpret_cast<float4*>(out)[i] = o;
  }
}

extern "C" void kernel_launch(void* const* d_in, const int* in_sizes, int n_in,
                              void* d_out, int out_size, void* d_ws, size_t ws_size,
                              hipStream_t stream) {
  const float* x = (const float*)d_in[0];
  const float* rw = (const float*)d_in[1];
  const float* up = (const float*)d_in[2];
  const float* down = (const float*)d_in[3];
  float* out = (float*)d_out;

  char* ws = (char*)d_ws;
  bf16* xb = (bf16*)(ws);                       // 16 MB
  bf16* upb = (bf16*)(ws + 16777216);           // 64 MB
  bf16* downb = (bf16*)(ws + 83886080);         // 32 MB
  bf16* y1 = (bf16*)(ws + 117440512);           // 72 MB (18432 x ED bf16)
  bf16* part = (bf16*)(ws + 192937984);         // 36 MB (18432 x HID bf16)
  char* misc = ws + 268435456;
  int2* top2i = (int2*)(misc);
  float2* top2w = (float2*)(misc + 65536);
  int* list = (int*)(misc + 131072);
  int2* posArr = (int2*)(misc + 262144);
  int* tile_e = (int*)(misc + 327680);
  int* meta = (int*)(misc + 331776);

  cvt2_kernel<<<2048, 256, 0, stream>>>(up, down, upb, downb);
  router_kernel<<<T_TOKENS, 64, 0, stream>>>(x, rw, xb, top2i, top2w);
  build_lists<<<1, 512, 0, stream>>>(top2i, list, posArr, tile_e, meta);

  gemm1_silu<<<MAXT256 * 32, 512, 0, stream>>>(xb, upb, y1, list, tile_e, meta);
  gemm2_part<<<MAXT256 * 8, 512, 0, stream>>>(y1, downb, part, tile_e, meta);
  combine_kernel<<<2048, 256, 0, stream>>>(part, posArr, top2w, out);
}

// Round 9
// 413.062 us; speedup vs baseline: 1.1126x; 1.1126x over previous
//
#include <hip/hip_runtime.h>
#include <hip/hip_bf16.h>

// MoE FFN, grouped sparse dispatch (top-2 of 8).
// R6 GEMM shapes (measured-best): gemm1 BM=256 x 128-dual-col panels, gemm2 256x256.
// R4/R6 schedule: dbuf + burst stage + counted vmcnt + raw barriers + setprio.
// T2 LDS XOR-swizzle both-sides. bf16 partials + fused weight cvt (R8 wins).

#define T_TOKENS 8192
#define HID 1024
#define NEXP 8
#define ED 2048
#define ED2 4096
#define MAXT256 72      // max 256-row tiles

typedef __hip_bfloat16 bf16;
typedef __attribute__((ext_vector_type(8))) short bf16x8;
typedef __attribute__((ext_vector_type(4))) float f32x4;

#define WAITVM(N) asm volatile("s_waitcnt vmcnt(" #N ")" ::: "memory")
#define BAR() asm volatile("s_barrier" ::: "memory")

__device__ __forceinline__ void gload_lds16(const void* g, void* lds) {
  __builtin_amdgcn_global_load_lds(
      (const __attribute__((address_space(1))) void*)g,
      (__attribute__((address_space(3))) void*)lds, 16, 0, 0);
}

__device__ __forceinline__ bf16x8 lds_read_swz(const bf16* base, int row, int kb) {
  int off = row * 128 + (kb ^ ((row & 7) << 4));
  return *reinterpret_cast<const bf16x8*>(reinterpret_cast<const char*>(base) + off);
}

// ---------------- f32 -> bf16 conversion (both weight tensors, one launch) ----------------
__global__ void cvt2_kernel(const float* __restrict__ up, const float* __restrict__ down,
                            bf16* __restrict__ upb, bf16* __restrict__ downb) {
  const int n_up4 = (NEXP * ED2 * HID) / 4;
  const int n_total = n_up4 + (NEXP * HID * ED) / 4;
  int idx = blockIdx.x * blockDim.x + threadIdx.x;
  int stride = gridDim.x * blockDim.x;
  for (int i = idx; i < n_total; i += stride) {
    const float4 v = (i < n_up4) ? reinterpret_cast<const float4*>(up)[i]
                                 : reinterpret_cast<const float4*>(down)[i - n_up4];
    bf16 h0 = __float2bfloat16(v.x), h1 = __float2bfloat16(v.y);
    bf16 h2 = __float2bfloat16(v.z), h3 = __float2bfloat16(v.w);
    ushort4 o;
    o.x = *reinterpret_cast<unsigned short*>(&h0);
    o.y = *reinterpret_cast<unsigned short*>(&h1);
    o.z = *reinterpret_cast<unsigned short*>(&h2);
    o.w = *reinterpret_cast<unsigned short*>(&h3);
    if (i < n_up4) reinterpret_cast<ushort4*>(upb)[i] = o;
    else reinterpret_cast<ushort4*>(downb)[i - n_up4] = o;
  }
}

// ---------------- router (+ x -> bf16) ----------------
__global__ __launch_bounds__(64) void router_kernel(const float* __restrict__ x,
                                                    const float* __restrict__ rw,
                                                    bf16* __restrict__ xb,
                                                    int2* __restrict__ top2i,
                                                    float2* __restrict__ top2w) {
  const int t = blockIdx.x;
  const int lane = threadIdx.x;
  const float* xr = x + (size_t)t * HID;
  float xv[16];
#pragma unroll
  for (int i = 0; i < 16; i++) xv[i] = xr[lane + 64 * i];
#pragma unroll
  for (int i = 0; i < 16; i++) xb[(size_t)t * HID + lane + 64 * i] = __float2bfloat16(xv[i]);
  float logit[NEXP];
#pragma unroll
  for (int e = 0; e < NEXP; e++) {
    const float* r = rw + e * HID;
    float p = 0.f;
#pragma unroll
    for (int i = 0; i < 16; i++) p += xv[i] * r[lane + 64 * i];
#pragma unroll
    for (int off = 32; off > 0; off >>= 1) p += __shfl_down(p, off);
    logit[e] = __shfl(p, 0);
  }
  if (lane == 0) {
    int i0 = 0;
    for (int e = 1; e < NEXP; e++) if (logit[e] > logit[i0]) i0 = e;
    int i1 = (i0 == 0) ? 1 : 0;
    for (int e = 0; e < NEXP; e++) if (e != i0 && logit[e] > logit[i1]) i1 = e;
    float m = fmaxf(logit[i0], logit[i1]);
    float p0 = expf(logit[i0] - m), p1 = expf(logit[i1] - m);
    float s = p0 + p1;
    top2i[t] = make_int2(i0, i1);
    top2w[t] = make_float2(p0 / s, p1 / s);
  }
}

// ---------------- list build (pad to 256) ----------------
__global__ __launch_bounds__(512) void build_lists(const int2* __restrict__ top2i,
                                                   int* __restrict__ list,
                                                   int2* __restrict__ posArr,
                                                   int* __restrict__ tile_e,
                                                   int* __restrict__ meta) {
  __shared__ int s_cnt[NEXP];
  __shared__ int s_base[NEXP + 1];
  const int e = threadIdx.x >> 6;
  const int lane = threadIdx.x & 63;

  int cnt = 0;
  for (int c = 0; c < T_TOKENS / 64; c++) {
    const int t = c * 64 + lane;
    int2 ti = top2i[t];
    cnt += __popcll(__ballot((ti.x == e) || (ti.y == e)));
  }
  if (lane == 0) s_cnt[e] = cnt;
  __syncthreads();
  if (threadIdx.x == 0) {
    int acc = 0;
    for (int i = 0; i < NEXP; i++) {
      s_base[i] = acc;
      acc += (s_cnt[i] + 255) & ~255;
    }
    s_base[NEXP] = acc;
    meta[0] = acc / 256;
  }
  __syncthreads();
  const int ebase = s_base[e];
  const int padded = (s_cnt[e] + 255) & ~255;

  int base = 0;
  for (int c = 0; c < T_TOKENS / 64; c++) {
    const int t = c * 64 + lane;
    int2 ti = top2i[t];
    bool a0 = (ti.x == e);
    bool assigned = a0 || (ti.y == e);
    unsigned long long bal = __ballot(assigned);
    int prefix = __popcll(bal & ((1ull << lane) - 1ull));
    if (assigned) {
      int g = ebase + base + prefix;
      list[g] = t;
      if (a0) posArr[t].x = g; else posArr[t].y = g;
    }
    base += __popcll(bal);
  }
  for (int p = base + lane; p < padded; p += 64) list[ebase + p] = 0;
  for (int i = lane; i < padded / 256; i += 64) tile_e[ebase / 256 + i] = e;
}

// ---------------- GEMM1: y1 = silu(x@Wg^T)*(x@Wu^T), grouped, 256 x (128 dual) ----------------
// 8 waves 2M x 4N; per wave 128 rows x 32 D-cols, dual (gate+up) accumulators.
__global__ __launch_bounds__(512) void gemm1_silu(const bf16* __restrict__ A,
                                                  const bf16* __restrict__ Ball,
                                                  bf16* __restrict__ Y,
                                                  const int* __restrict__ list,
                                                  const int* __restrict__ tile_e,
                                                  const int* __restrict__ meta) {
  __shared__ bf16 sA[2][256 * 64];
  __shared__ bf16 sBg[2][128 * 64];
  __shared__ bf16 sBu[2][128 * 64];
  const int nwg = MAXT256 * 16;               // 1152, %8==0
  const int id2 = ((int)blockIdx.x % 8) * (nwg / 8) + (int)blockIdx.x / 8;  // T1
  const int dn = id2 % 16;
  const int tile = id2 / 16;
  if (tile >= meta[0]) return;
  const bf16* B = Ball + (size_t)tile_e[tile] * (ED2 * HID);
  const int rowbase = tile * 256;
  const int w = threadIdx.x >> 6, lane = threadIdx.x & 63;
  const int wm = w >> 2, wn = w & 3;
  const int srcswz = 16 * ((lane & 7) ^ ((lane >> 3) & 7));
  const int dn0 = dn * 128;

  int tok[4];
#pragma unroll
  for (int i = 0; i < 4; i++) tok[i] = list[rowbase + w * 32 + i * 8 + (lane >> 3)];

  f32x4 accg[8][2] = {};
  f32x4 accu[8][2] = {};

  auto stage = [&](int kt, int buf) {
    const int kb0 = kt * 128;  // k-byte base
#pragma unroll
    for (int i = 0; i < 4; i++)
      gload_lds16((const char*)A + (size_t)tok[i] * (HID * 2) + kb0 + srcswz,
                  (char*)&sA[buf][0] + (w * 32 + i * 8) * 128);
#pragma unroll
    for (int i = 0; i < 2; i++) {
      const int c = w * 2 + i;
      const int grow = dn0 + c * 8 + (lane >> 3);
      gload_lds16((const char*)B + (size_t)grow * (HID * 2) + kb0 + srcswz,
                  (char*)&sBg[buf][0] + c * 1024);
      gload_lds16((const char*)B + (size_t)(ED + grow) * (HID * 2) + kb0 + srcswz,
                  (char*)&sBu[buf][0] + c * 1024);
    }
  };

  const int NT = HID / 64;  // 16
  stage(0, 0);
  for (int t = 0; t < NT; ++t) {
    const int cur = t & 1;
    if (t + 1 < NT) { stage(t + 1, cur ^ 1); WAITVM(8); }
    else { WAITVM(0); }
    BAR();
    const bf16* pA = &sA[cur][0];
    const bf16* pBg = &sBg[cur][0];
    const bf16* pBu = &sBu[cur][0];
    const int arow0 = wm * 128 + (lane & 15);
    const int brow0 = wn * 32 + (lane & 15);
    const int kb0 = (lane >> 4) * 16;
    bf16x8 a[4][2], bg[2][2], bu[2][2];
    // q0: A mh0 + Bg reads, gate MFMA (m 0..3)
#pragma unroll
    for (int m = 0; m < 4; m++)
#pragma unroll
      for (int ks = 0; ks < 2; ks++) a[m][ks] = lds_read_swz(pA, arow0 + m * 16, kb0 + ks * 64);
#pragma unroll
    for (int n = 0; n < 2; n++)
#pragma unroll
      for (int ks = 0; ks < 2; ks++) bg[n][ks] = lds_read_swz(pBg, brow0 + n * 16, kb0 + ks * 64);
    __builtin_amdgcn_s_setprio(1);
#pragma unroll
    for (int m = 0; m < 4; m++)
#pragma unroll
      for (int n = 0; n < 2; n++)
#pragma unroll
        for (int ks = 0; ks < 2; ks++)
          accg[m][n] = __builtin_amdgcn_mfma_f32_16x16x32_bf16(a[m][ks], bg[n][ks], accg[m][n], 0, 0, 0);
    __builtin_amdgcn_s_setprio(0);
    // q1: Bu reads, up MFMA (m 0..3)
#pragma unroll
    for (int n = 0; n < 2; n++)
#pragma unroll
      for (int ks = 0; ks < 2; ks++) bu[n][ks] = lds_read_swz(pBu, brow0 + n * 16, kb0 + ks * 64);
    __builtin_amdgcn_s_setprio(1);
#pragma unroll
    for (int m = 0; m < 4; m++)
#pragma unroll
      for (int n = 0; n < 2; n++)
#pragma unroll
        for (int ks = 0; ks < 2; ks++)
          accu[m][n] = __builtin_amdgcn_mfma_f32_16x16x32_bf16(a[m][ks], bu[n][ks], accu[m][n], 0, 0, 0);
    __builtin_amdgcn_s_setprio(0);
    // q2: A mh1 reads, gate MFMA (m 4..7)
#pragma unroll
    for (int m = 0; m < 4; m++)
#pragma unroll
      for (int ks = 0; ks < 2; ks++) a[m][ks] = lds_read_swz(pA, arow0 + 64 + m * 16, kb0 + ks * 64);
    __builtin_amdgcn_s_setprio(1);
#pragma unroll
    for (int m = 0; m < 4; m++)
#pragma unroll
      for (int n = 0; n < 2; n++)
#pragma unroll
        for (int ks = 0; ks < 2; ks++)
          accg[m + 4][n] = __builtin_amdgcn_mfma_f32_16x16x32_bf16(a[m][ks], bg[n][ks], accg[m + 4][n], 0, 0, 0);
    __builtin_amdgcn_s_setprio(0);
    // q3: up MFMA (m 4..7)
    __builtin_amdgcn_s_setprio(1);
#pragma unroll
    for (int m = 0; m < 4; m++)
#pragma unroll
      for (int n = 0; n < 2; n++)
#pragma unroll
        for (int ks = 0; ks < 2; ks++)
          accu[m + 4][n] = __builtin_amdgcn_mfma_f32_16x16x32_bf16(a[m][ks], bu[n][ks], accu[m + 4][n], 0, 0, 0);
    __builtin_amdgcn_s_setprio(0);
    BAR();
  }
  // epilogue: silu(g)*u -> bf16
#pragma unroll
  for (int m = 0; m < 8; m++)
#pragma unroll
    for (int n = 0; n < 2; n++) {
      const int row = rowbase + wm * 128 + (m & 3) * 16 + (m >> 2) * 64 + (lane >> 4) * 4;
      const int col = dn0 + wn * 32 + n * 16 + (lane & 15);
#pragma unroll
      for (int r = 0; r < 4; r++) {
        float g = accg[m][n][r];
        float u = accu[m][n][r];
        float s = g * __builtin_amdgcn_rcpf(1.f + exp2f(g * -1.44269504f));
        Y[(size_t)(row + r) * ED + col] = __float2bfloat16(s * u);
      }
    }
}

// ---------------- GEMM2: part = y1 @ down_e^T (bf16, unweighted), 256x256 ----------------
// 8 waves 2M x 4N; per wave 128 rows x 64 cols.
__global__ __launch_bounds__(512) void gemm2_part(const bf16* __restrict__ A,
                                                  const bf16* __restrict__ Ball,
                                                  bf16* __restrict__ part,
                                                  const int* __restrict__ tile_e,
                                                  const int* __restrict__ meta) {
  __shared__ bf16 sA[2][256 * 64];
  __shared__ bf16 sB[2][256 * 64];
  const int nwg = MAXT256 * 4;                // 288, %8==0
  const int id2 = ((int)blockIdx.x % 8) * (nwg / 8) + (int)blockIdx.x / 8;  // T1
  const int bn = id2 & 3;
  const int tile = id2 >> 2;
  if (tile >= meta[0]) return;
  const bf16* B = Ball + (size_t)tile_e[tile] * (HID * ED);
  const int rowbase = tile * 256;
  const int w = threadIdx.x >> 6, lane = threadIdx.x & 63;
  const int wm = w >> 2, wn = w & 3;
  const int srcswz = 16 * ((lane & 7) ^ ((lane >> 3) & 7));
  const int bn0 = bn * 256;

  f32x4 acc[8][4] = {};

  auto stage = [&](int kt, int buf) {
    const int kb0 = kt * 128;
#pragma unroll
    for (int i = 0; i < 4; i++) {
      const int c = w * 4 + i;  // 0..31
      gload_lds16((const char*)A + (size_t)(rowbase + c * 8 + (lane >> 3)) * (ED * 2) + kb0 + srcswz,
                  (char*)&sA[buf][0] + c * 1024);
      gload_lds16((const char*)B + (size_t)(bn0 + c * 8 + (lane >> 3)) * (ED * 2) + kb0 + srcswz,
                  (char*)&sB[buf][0] + c * 1024);
    }
  };

  const int NT = ED / 64;  // 32
  stage(0, 0);
  for (int t = 0; t < NT; ++t) {
    const int cur = t & 1;
    if (t + 1 < NT) { stage(t + 1, cur ^ 1); WAITVM(8); }
    else { WAITVM(0); }
    BAR();
    const bf16* pA = &sA[cur][0];
    const bf16* pB = &sB[cur][0];
    const int arow0 = wm * 128 + (lane & 15);
    const int brow0 = wn * 64 + (lane & 15);
    const int kb0 = (lane >> 4) * 16;
    bf16x8 a[4][2], b[4][2];
#pragma unroll
    for (int n = 0; n < 4; n++)
#pragma unroll
      for (int ks = 0; ks < 2; ks++) b[n][ks] = lds_read_swz(pB, brow0 + n * 16, kb0 + ks * 64);
    // mh0: m 0..3
#pragma unroll
    for (int m = 0; m < 4; m++)
#pragma unroll
      for (int ks = 0; ks < 2; ks++) a[m][ks] = lds_read_swz(pA, arow0 + m * 16, kb0 + ks * 64);
    __builtin_amdgcn_s_setprio(1);
#pragma unroll
    for (int m = 0; m < 4; m++)
#pragma unroll
      for (int n = 0; n < 4; n++)
#pragma unroll
        for (int ks = 0; ks < 2; ks++)
          acc[m][n] = __builtin_amdgcn_mfma_f32_16x16x32_bf16(a[m][ks], b[n][ks], acc[m][n], 0, 0, 0);
    __builtin_amdgcn_s_setprio(0);
    // mh1: m 4..7
#pragma unroll
    for (int m = 0; m < 4; m++)
#pragma unroll
      for (int ks = 0; ks < 2; ks++) a[m][ks] = lds_read_swz(pA, arow0 + 64 + m * 16, kb0 + ks * 64);
    __builtin_amdgcn_s_setprio(1);
#pragma unroll
    for (int m = 0; m < 4; m++)
#pragma unroll
      for (int n = 0; n < 4; n++)
#pragma unroll
        for (int ks = 0; ks < 2; ks++)
          acc[m + 4][n] = __builtin_amdgcn_mfma_f32_16x16x32_bf16(a[m][ks], b[n][ks], acc[m + 4][n], 0, 0, 0);
    __builtin_amdgcn_s_setprio(0);
    BAR();
  }
#pragma unroll
  for (int m = 0; m < 8; m++)
#pragma unroll
    for (int n = 0; n < 4; n++) {
      const int row = rowbase + wm * 128 + (m & 3) * 16 + (m >> 2) * 64 + (lane >> 4) * 4;
      const int col = bn0 + wn * 64 + n * 16 + (lane & 15);
#pragma unroll
      for (int r = 0; r < 4; r++)
        part[(size_t)(row + r) * HID + col] = __float2bfloat16(acc[m][n][r]);
    }
}

// ---------------- combine: out[t] = w0*part[pos0] + w1*part[pos1] (bf16 partials) ----------------
__global__ void combine_kernel(const bf16* __restrict__ part,
                               const int2* __restrict__ posArr,
                               const float2* __restrict__ top2w,
                               float* __restrict__ out) {
  const int total = T_TOKENS * (HID / 4);
  int idx = blockIdx.x * blockDim.x + threadIdx.x;
  int stride = gridDim.x * blockDim.x;
  for (int i = idx; i < total; i += stride) {
    const int t = i >> 8;
    const int c = i & 255;
    int2 p = posArr[t];
    float2 w = top2w[t];
    ushort4 av = reinterpret_cast<const ushort4*>(part)[(size_t)p.x * 256 + c];
    ushort4 bv = reinterpret_cast<const ushort4*>(part)[(size_t)p.y * 256 + c];
    float4 o;
    o.x = w.x * __bfloat162float(*reinterpret_cast<bf16*>(&av.x)) + w.y * __bfloat162float(*reinterpret_cast<bf16*>(&bv.x));
    o.y = w.x * __bfloat162float(*reinterpret_cast<bf16*>(&av.y)) + w.y * __bfloat162float(*reinterpret_cast<bf16*>(&bv.y));
    o.z = w.x * __bfloat162float(*reinterpret_cast<bf16*>(&av.z)) + w.y * __bfloat162float(*reinterpret_cast<bf16*>(&bv.z));
    o.w = w.x * __bfloat162float(*reinterpret_cast<bf16*>(&av.w)) + w.y * __bfloat162float(*reinterpret_cast<bf16*>(&bv.w));
    reinterpret_cast<float4*>(out)[i] = o;
  }
}

extern "C" void kernel_launch(void* const* d_in, const int* in_sizes, int n_in,
                              void* d_out, int out_size, void* d_ws, size_t ws_size,
                              hipStream_t stream) {
  const float* x = (const float*)d_in[0];
  const float* rw = (const float*)d_in[1];
  const float* up = (const float*)d_in[2];
  const float* down = (const float*)d_in[3];
  float* out = (float*)d_out;

  char* ws = (char*)d_ws;
  bf16* xb = (bf16*)(ws);                       // 16 MB
  bf16* upb = (bf16*)(ws + 16777216);           // 64 MB
  bf16* downb = (bf16*)(ws + 83886080);         // 32 MB
  bf16* y1 = (bf16*)(ws + 117440512);           // 72 MB (18432 x ED bf16)
  bf16* part = (bf16*)(ws + 192937984);         // 36 MB (18432 x HID bf16)
  char* misc = ws + 268435456;
  int2* top2i = (int2*)(misc);
  float2* top2w = (float2*)(misc + 65536);
  int* list = (int*)(misc + 131072);
  int2* posArr = (int2*)(misc + 262144);
  int* tile_e = (int*)(misc + 327680);
  int* meta = (int*)(misc + 331776);

  cvt2_kernel<<<2048, 256, 0, stream>>>(up, down, upb, downb);
  router_kernel<<<T_TOKENS, 64, 0, stream>>>(x, rw, xb, top2i, top2w);
  build_lists<<<1, 512, 0, stream>>>(top2i, list, posArr, tile_e, meta);

  gemm1_silu<<<MAXT256 * 16, 512, 0, stream>>>(xb, upb, y1, list, tile_e, meta);
  gemm2_part<<<MAXT256 * 4, 512, 0, stream>>>(y1, downb, part, tile_e, meta);
  combine_kernel<<<2048, 256, 0, stream>>>(part, posArr, top2w, out);
}